// Round 1
// baseline (757.092 us; speedup 1.0000x reference)
//
#include <hip/hip_runtime.h>
#include <stdint.h>

#define NUM_HEADS 12
#define HEAD_DIM  64
#define HWDIM     56
#define PHDIM     28
#define NTOK      785     // 28*28+1
#define NIN       3137    // 56*56+1
#define BATCH     16
#define DMODEL    768
#define BHCNT     192     // BATCH*NUM_HEADS

typedef __attribute__((ext_vector_type(8))) short bf16x8;
typedef __attribute__((ext_vector_type(4))) float f32x4;

static __device__ __forceinline__ float bf2f(short s) {
  unsigned u = ((unsigned)(unsigned short)s) << 16;
  float f; __builtin_memcpy(&f, &u, 4); return f;
}
static __device__ __forceinline__ short f2bf(float f) {
  unsigned u; __builtin_memcpy(&u, &f, 4);
  unsigned r = u + 0x7FFFu + ((u >> 16) & 1u);
  return (short)(r >> 16);
}
static __device__ __forceinline__ float wredsum64(float v) {
#pragma unroll
  for (int m = 32; m >= 1; m >>= 1) v += __shfl_xor(v, m);
  return v;
}

// ---------------------------------------------------------------- pool + LN
__global__ __launch_bounds__(256) void pool_ln_kernel(
    const float* __restrict__ x,
    const float* __restrict__ wq9, const float* __restrict__ wk9, const float* __restrict__ wv9,
    const float* __restrict__ gq, const float* __restrict__ bq,
    const float* __restrict__ gk, const float* __restrict__ bk,
    const float* __restrict__ gv, const float* __restrict__ bv,
    short* __restrict__ Pq, short* __restrict__ Pk, short* __restrict__ Pv)
{
  int blk = blockIdx.x;             // b*NTOK + n
  int b = blk / NTOK, n = blk % NTOK;
  int wid = threadIdx.x >> 6, lane = threadIdx.x & 63;
  int c = lane;
  for (int hs = 0; hs < 3; ++hs) {
    int h = wid + 4 * hs;
    float aq, ak, av;
    if (n == 0) {
      float v0 = x[((size_t)b * NIN + 0) * DMODEL + h * HEAD_DIM + c];
      aq = ak = av = v0;
    } else {
      int s = n - 1;
      int i = s / PHDIM, j = s % PHDIM;
      aq = ak = av = 0.f;
#pragma unroll
      for (int di = 0; di < 3; ++di) {
        int ii = 2 * i - 1 + di;
        if (ii < 0 || ii >= HWDIM) continue;
#pragma unroll
        for (int dj = 0; dj < 3; ++dj) {
          int jj = 2 * j - 1 + dj;
          if (jj < 0 || jj >= HWDIM) continue;
          float xin = x[((size_t)b * NIN + 1 + ii * HWDIM + jj) * DMODEL + h * HEAD_DIM + c];
          int tap = di * 3 + dj;
          aq += wq9[c * 9 + tap] * xin;
          ak += wk9[c * 9 + tap] * xin;
          av += wv9[c * 9 + tap] * xin;
        }
      }
    }
    size_t oo = ((size_t)b * NTOK + n) * DMODEL + h * HEAD_DIM + c;
    {
      float mn = wredsum64(aq) * (1.f / 64.f);
      float d = aq - mn;
      float vv = wredsum64(d * d) * (1.f / 64.f);
      Pq[oo] = f2bf(d * rsqrtf(vv + 1e-5f) * gq[c] + bq[c]);
    }
    {
      float mn = wredsum64(ak) * (1.f / 64.f);
      float d = ak - mn;
      float vv = wredsum64(d * d) * (1.f / 64.f);
      Pk[oo] = f2bf(d * rsqrtf(vv + 1e-5f) * gk[c] + bk[c]);
    }
    {
      float mn = wredsum64(av) * (1.f / 64.f);
      float d = av - mn;
      float vv = wredsum64(d * d) * (1.f / 64.f);
      Pv[oo] = f2bf(d * rsqrtf(vv + 1e-5f) * gv[c] + bv[c]);
    }
  }
}

// ------------------------------------------------- weight transpose fp32->bf16
__global__ __launch_bounds__(256) void trans_kernel(
    const float* __restrict__ s0, const float* __restrict__ s1,
    const float* __restrict__ s2, const float* __restrict__ s3,
    short* __restrict__ d0, short* __restrict__ d1,
    short* __restrict__ d2, short* __restrict__ d3)
{
  __shared__ float tile[32][33];
  int z = blockIdx.z;
  const float* s = (z == 0) ? s0 : (z == 1) ? s1 : (z == 2) ? s2 : s3;
  short* d = (z == 0) ? d0 : (z == 1) ? d1 : (z == 2) ? d2 : d3;
  int k0 = blockIdx.x * 32, n0 = blockIdx.y * 32;
  int tx = threadIdx.x, ty = threadIdx.y;   // 32 x 8
#pragma unroll
  for (int jj = 0; jj < 4; ++jj)
    tile[ty + jj * 8][tx] = s[(size_t)(k0 + ty + jj * 8) * DMODEL + n0 + tx];
  __syncthreads();
#pragma unroll
  for (int jj = 0; jj < 4; ++jj)
    d[(size_t)(n0 + ty + jj * 8) * DMODEL + k0 + tx] = f2bf(tile[tx][ty + jj * 8]);
}

// ------------------------------------------------------------- bf16 MFMA GEMM
// C[M,768] = A[M,768] @ Bt[768,768]^T + bias ; mode0: fp32 row-major out
// mode1: bf16 out in (B,12,785,64) layout
#define BK 32
#define LDSP 40   // padded LDS row length (shorts) -> 80B rows, ~2-way conflicts
__global__ __launch_bounds__(256) void gemm_bt_kernel(
    const short* __restrict__ A, const short* __restrict__ Bt,
    const float* __restrict__ bias, void* __restrict__ outp,
    int M, int mode)
{
  const int K = DMODEL, N = DMODEL;
  __shared__ short As[128 * LDSP];
  __shared__ short Bs[128 * LDSP];
  int tid = threadIdx.x;
  int wid = tid >> 6, lane = tid & 63;
  int wm = wid >> 1, wn = wid & 1;
  int rowbase = blockIdx.x * 128;
  int colbase = blockIdx.y * 128;

  f32x4 acc[4][4];
#pragma unroll
  for (int i = 0; i < 4; ++i)
#pragma unroll
    for (int j = 0; j < 4; ++j) acc[i][j] = (f32x4){0.f, 0.f, 0.f, 0.f};

  int srow = tid >> 2;            // 0..63
  int scol = (tid & 3) * 8;       // 0,8,16,24
  int ar0 = rowbase + srow;       if (ar0 > M - 1) ar0 = M - 1;
  int ar1 = rowbase + 64 + srow;  if (ar1 > M - 1) ar1 = M - 1;
  const short* Ag0 = A + (size_t)ar0 * K + scol;
  const short* Ag1 = A + (size_t)ar1 * K + scol;
  const short* Bg0 = Bt + (size_t)(colbase + srow) * K + scol;
  const short* Bg1 = Bt + (size_t)(colbase + 64 + srow) * K + scol;
  short* Aw0 = &As[srow * LDSP + scol];
  short* Aw1 = &As[(64 + srow) * LDSP + scol];
  short* Bw0 = &Bs[srow * LDSP + scol];
  short* Bw1 = &Bs[(64 + srow) * LDSP + scol];

  for (int kt = 0; kt < K; kt += BK) {
    __syncthreads();
    *(bf16x8*)Aw0 = *(const bf16x8*)(Ag0 + kt);
    *(bf16x8*)Aw1 = *(const bf16x8*)(Ag1 + kt);
    *(bf16x8*)Bw0 = *(const bf16x8*)(Bg0 + kt);
    *(bf16x8*)Bw1 = *(const bf16x8*)(Bg1 + kt);
    __syncthreads();
    bf16x8 aFrag[4], bFrag[4];
#pragma unroll
    for (int mi = 0; mi < 4; ++mi)
      aFrag[mi] = *(const bf16x8*)&As[(wm * 64 + mi * 16 + (lane & 15)) * LDSP + (lane >> 4) * 8];
#pragma unroll
    for (int ni = 0; ni < 4; ++ni)
      bFrag[ni] = *(const bf16x8*)&Bs[(wn * 64 + ni * 16 + (lane & 15)) * LDSP + (lane >> 4) * 8];
#pragma unroll
    for (int mi = 0; mi < 4; ++mi)
#pragma unroll
      for (int ni = 0; ni < 4; ++ni)
        acc[mi][ni] = __builtin_amdgcn_mfma_f32_16x16x32_bf16(aFrag[mi], bFrag[ni], acc[mi][ni], 0, 0, 0);
  }

#pragma unroll
  for (int mi = 0; mi < 4; ++mi)
#pragma unroll
    for (int ni = 0; ni < 4; ++ni)
#pragma unroll
      for (int r = 0; r < 4; ++r) {
        int row = rowbase + wm * 64 + mi * 16 + (lane >> 4) * 4 + r;
        int col = colbase + wn * 64 + ni * 16 + (lane & 15);
        if (row < M) {
          float v = acc[mi][ni][r] + bias[col];
          if (mode == 0) {
            ((float*)outp)[(size_t)row * N + col] = v;
          } else {
            int bb = row / NTOK, nn = row % NTOK;
            int hh = col >> 6, cc = col & 63;
            ((short*)outp)[(((size_t)(bb * NUM_HEADS + hh) * NTOK + nn) << 6) + cc] = f2bf(v);
          }
        }
      }
}

// -------------------------------------------------------- rel-pos bias tables
// RelH[bh, qs, ki] = sum_c q[bh,1+qs,c] * rel_pos_h[i-ki+27, c]   (i = qs/28)
// RelW[bh, qs, kj] = sum_c q[bh,1+qs,c] * rel_pos_w[j-kj+27, c]   (j = qs%28)
__global__ __launch_bounds__(256) void relbias_kernel(
    const short* __restrict__ qh, const float* __restrict__ rph,
    const float* __restrict__ rpw, float* __restrict__ RelH, float* __restrict__ RelW)
{
  int line = blockIdx.x;   // i (mode0) or j (mode1)
  int bh = blockIdx.y;
  int mode = blockIdx.z;
  __shared__ float qt_s[28 * 65];
  __shared__ float rt_s[28 * 65];
  int tid = threadIdx.x;
  const float* rp = (mode == 0) ? rph : rpw;
  for (int idx = tid; idx < 28 * 64; idx += 256) {
    int rr = idx >> 6, c = idx & 63;
    int qi = (mode == 0) ? (1 + line * PHDIM + rr) : (1 + rr * PHDIM + line);
    qt_s[rr * 65 + c] = bf2f(qh[((size_t)bh * NTOK + qi) * HEAD_DIM + c]);
    rt_s[rr * 65 + c] = rp[(line - rr + 27) * HEAD_DIM + c];
  }
  __syncthreads();
  for (int o = tid; o < 784; o += 256) {
    int rr = o / PHDIM, kk = o % PHDIM;
    float s = 0.f;
#pragma unroll
    for (int c = 0; c < 64; ++c) s += qt_s[rr * 65 + c] * rt_s[kk * 65 + c];
    if (mode == 0) {
      int qrow = line * PHDIM + rr;
      RelH[((size_t)bh * 784 + qrow) * PHDIM + kk] = s;
    } else {
      int qrow = rr * PHDIM + line;
      RelW[((size_t)bh * 784 + qrow) * PHDIM + kk] = s;
    }
  }
}

// ------------------------------------------------------------ flash attention
__global__ __launch_bounds__(256) void flash_kernel(
    const short* __restrict__ qh, const short* __restrict__ kh, const short* __restrict__ vh,
    const float* __restrict__ RelH, const float* __restrict__ RelW,
    short* __restrict__ Afin)
{
  int qt = blockIdx.x;           // 0..12
  int bh = blockIdx.y;           // 0..191
  int qbase = qt * 64;
  int tid = threadIdx.x, wid = tid >> 6, lane = tid & 63;

  __shared__ float relh[64 * 28];
  __shared__ float relw[64 * 28];
  __shared__ short vt[64 * 32];          // swizzled Vt[d][key]
  __shared__ short pbuf[4][16 * 32];     // per-wave swizzled P

  for (int idx = tid; idx < 64 * 28; idx += 256) {
    int ql = idx / 28, kk = idx % 28;
    int qi = qbase + ql;
    float rh = 0.f, rw = 0.f;
    if (qi >= 1 && qi < NTOK) {
      rh = RelH[((size_t)bh * 784 + (qi - 1)) * PHDIM + kk];
      rw = RelW[((size_t)bh * 784 + (qi - 1)) * PHDIM + kk];
    }
    relh[idx] = rh; relw[idx] = rw;
  }

  int qi0 = qbase + wid * 16 + (lane & 15);
  int qiq = (qi0 < NTOK) ? qi0 : (NTOK - 1);
  const short* qrow = qh + ((size_t)bh * NTOK + qiq) * HEAD_DIM;
  bf16x8 aq0 = *(const bf16x8*)(qrow + (lane >> 4) * 8);
  bf16x8 aq1 = *(const bf16x8*)(qrow + 32 + (lane >> 4) * 8);

  float m[4], lsum[4];
  f32x4 acc[4];
#pragma unroll
  for (int r = 0; r < 4; ++r) { m[r] = -1e30f; lsum[r] = 0.f; }
#pragma unroll
  for (int ch = 0; ch < 4; ++ch) acc[ch] = (f32x4){0.f, 0.f, 0.f, 0.f};

  const float scale = 0.125f;
  int vkey = tid & 31, vcg = tid >> 5;

  for (int step = 0; step < 25; ++step) {
    int kvb = step * 32;
    __syncthreads();
    { // stage V transposed (swizzled)
      int kv = kvb + vkey;
      bf16x8 v8 = {0, 0, 0, 0, 0, 0, 0, 0};
      if (kv < NTOK) v8 = *(const bf16x8*)(vh + ((size_t)bh * NTOK + kv) * HEAD_DIM + vcg * 8);
#pragma unroll
      for (int e = 0; e < 8; ++e) {
        int d = vcg * 8 + e;
        int byte = (d * 64 + vkey * 2) ^ ((d & 7) << 4);
        *(short*)((char*)vt + byte) = v8[e];
      }
    }
    __syncthreads();

    float pvals[2][4];
#pragma unroll
    for (int kt2 = 0; kt2 < 2; ++kt2) {
      int key = kvb + kt2 * 16 + (lane & 15);
      int keyc = (key < NTOK) ? key : (NTOK - 1);
      const short* krow = kh + ((size_t)bh * NTOK + keyc) * HEAD_DIM;
      bf16x8 bk0 = *(const bf16x8*)(krow + (lane >> 4) * 8);
      bf16x8 bk1 = *(const bf16x8*)(krow + 32 + (lane >> 4) * 8);
      f32x4 s = (f32x4){0.f, 0.f, 0.f, 0.f};
      s = __builtin_amdgcn_mfma_f32_16x16x32_bf16(aq0, bk0, s, 0, 0, 0);
      s = __builtin_amdgcn_mfma_f32_16x16x32_bf16(aq1, bk1, s, 0, 0, 0);
      int km1 = (key > 0) ? (key - 1) : 0;
      int ki = km1 / PHDIM, kj = km1 % PHDIM;
      bool kval = (key >= 1 && key < NTOK);
#pragma unroll
      for (int r = 0; r < 4; ++r) {
        int qrl = wid * 16 + (lane >> 4) * 4 + r;
        float v = s[r] * scale;
        if (kval) v += relh[qrl * 28 + ki] + relw[qrl * 28 + kj];
        if (key >= NTOK) v = -1e30f;
        pvals[kt2][r] = v;
      }
    }

#pragma unroll
    for (int r = 0; r < 4; ++r) {
      float mx = fmaxf(pvals[0][r], pvals[1][r]);
#pragma unroll
      for (int s2 = 1; s2 < 16; s2 <<= 1) mx = fmaxf(mx, __shfl_xor(mx, s2));
      float mnew = fmaxf(m[r], mx);
      float alpha = __expf(m[r] - mnew);
      m[r] = mnew;
      float p0 = __expf(pvals[0][r] - mnew);
      float p1 = __expf(pvals[1][r] - mnew);
      pvals[0][r] = p0; pvals[1][r] = p1;
      float ps = p0 + p1;
#pragma unroll
      for (int s2 = 1; s2 < 16; s2 <<= 1) ps += __shfl_xor(ps, s2);
      lsum[r] = lsum[r] * alpha + ps;
#pragma unroll
      for (int ch = 0; ch < 4; ++ch) acc[ch][r] *= alpha;
    }

    short* pw = pbuf[wid];
#pragma unroll
    for (int kt2 = 0; kt2 < 2; ++kt2)
#pragma unroll
      for (int r = 0; r < 4; ++r) {
        int row = (lane >> 4) * 4 + r;
        int byte = (row * 64 + (kt2 * 16 + (lane & 15)) * 2) ^ ((row & 7) << 4);
        *(short*)((char*)pw + byte) = f2bf(pvals[kt2][r]);
      }
    int prow = lane & 15;
    int pbyte = (prow * 64 + (lane >> 4) * 16) ^ ((prow & 7) << 4);
    bf16x8 pa = *(const bf16x8*)((char*)pw + pbyte);
#pragma unroll
    for (int ch = 0; ch < 4; ++ch) {
      int d = ch * 16 + (lane & 15);
      int vbyte = (d * 64 + (lane >> 4) * 16) ^ ((d & 7) << 4);
      bf16x8 bv = *(const bf16x8*)((char*)vt + vbyte);
      acc[ch] = __builtin_amdgcn_mfma_f32_16x16x32_bf16(pa, bv, acc[ch], 0, 0, 0);
    }
  }

  int b = bh / NUM_HEADS, h = bh % NUM_HEADS;
#pragma unroll
  for (int ch = 0; ch < 4; ++ch)
#pragma unroll
    for (int r = 0; r < 4; ++r) {
      int rowl = (lane >> 4) * 4 + r;
      int qi = qbase + wid * 16 + rowl;
      if (qi < NTOK) {
        int d = ch * 16 + (lane & 15);
        float o = acc[ch][r] / lsum[r];
        o += bf2f(qh[((size_t)bh * NTOK + qi) * HEAD_DIM + d]);
        Afin[((size_t)b * NTOK + qi) * DMODEL + h * HEAD_DIM + d] = f2bf(o);
      }
    }
}

// ------------------------------------------------------------------- launcher
extern "C" void kernel_launch(void* const* d_in, const int* in_sizes, int n_in,
                              void* d_out, int out_size, void* d_ws, size_t ws_size,
                              hipStream_t stream)
{
  (void)in_sizes; (void)n_in; (void)out_size; (void)ws_size;
  const float* x   = (const float*)d_in[0];
  const float* pqw = (const float*)d_in[1];
  const float* pkw = (const float*)d_in[2];
  const float* pvw = (const float*)d_in[3];
  const float* gq  = (const float*)d_in[4];
  const float* bq_ = (const float*)d_in[5];
  const float* gk  = (const float*)d_in[6];
  const float* bk_ = (const float*)d_in[7];
  const float* gv  = (const float*)d_in[8];
  const float* bv_ = (const float*)d_in[9];
  const float* wq  = (const float*)d_in[10];
  const float* bqp = (const float*)d_in[11];
  const float* wk  = (const float*)d_in[12];
  const float* bkp = (const float*)d_in[13];
  const float* wv  = (const float*)d_in[14];
  const float* bvp = (const float*)d_in[15];
  const float* wp  = (const float*)d_in[16];
  const float* bpp = (const float*)d_in[17];
  const float* rph = (const float*)d_in[18];
  const float* rpw = (const float*)d_in[19];

  char* ws = (char*)d_ws;
  size_t off = 0;
  auto alloc = [&](size_t bytes) -> void* {
    void* p = ws + off; off += (bytes + 255) & ~(size_t)255; return p;
  };
  const size_t MROWS = (size_t)BATCH * NTOK;   // 12560
  short* Pq  = (short*)alloc(MROWS * DMODEL * 2);
  short* Pk  = (short*)alloc(MROWS * DMODEL * 2);
  short* Pv  = (short*)alloc(MROWS * DMODEL * 2);
  short* WqT = (short*)alloc((size_t)DMODEL * DMODEL * 2);
  short* WkT = (short*)alloc((size_t)DMODEL * DMODEL * 2);
  short* WvT = (short*)alloc((size_t)DMODEL * DMODEL * 2);
  short* WpT = (short*)alloc((size_t)DMODEL * DMODEL * 2);
  short* qhd = (short*)alloc(MROWS * DMODEL * 2);
  short* khd = (short*)alloc(MROWS * DMODEL * 2);
  short* vhd = (short*)alloc(MROWS * DMODEL * 2);
  float* RelH = (float*)alloc((size_t)BHCNT * 784 * 28 * 4);
  float* RelW = (float*)alloc((size_t)BHCNT * 784 * 28 * 4);
  short* Afin = (short*)alloc(MROWS * DMODEL * 2);

  pool_ln_kernel<<<dim3(BATCH * NTOK), 256, 0, stream>>>(
      x, pqw, pkw, pvw, gq, bq_, gk, bk_, gv, bv_, Pq, Pk, Pv);
  trans_kernel<<<dim3(24, 24, 4), dim3(32, 8), 0, stream>>>(
      wq, wk, wv, wp, WqT, WkT, WvT, WpT);
  dim3 gg(99, 6);
  gemm_bt_kernel<<<gg, 256, 0, stream>>>(Pq, WqT, bqp, qhd, (int)MROWS, 1);
  gemm_bt_kernel<<<gg, 256, 0, stream>>>(Pk, WkT, bkp, khd, (int)MROWS, 1);
  gemm_bt_kernel<<<gg, 256, 0, stream>>>(Pv, WvT, bvp, vhd, (int)MROWS, 1);
  relbias_kernel<<<dim3(28, BHCNT, 2), 256, 0, stream>>>(qhd, rph, rpw, RelH, RelW);
  flash_kernel<<<dim3(13, BHCNT), 256, 0, stream>>>(qhd, khd, vhd, RelH, RelW, Afin);
  gemm_bt_kernel<<<gg, 256, 0, stream>>>(Afin, WpT, bpp, d_out, (int)MROWS, 0);
}

// Round 2
// 594.542 us; speedup vs baseline: 1.2734x; 1.2734x over previous
//
#include <hip/hip_runtime.h>
#include <stdint.h>

#define NUM_HEADS 12
#define HEAD_DIM  64
#define HWDIM     56
#define PHDIM     28
#define NTOK      785     // 28*28+1
#define NIN       3137    // 56*56+1
#define BATCH     16
#define DMODEL    768
#define BHCNT     192     // BATCH*NUM_HEADS

typedef __attribute__((ext_vector_type(8))) short bf16x8;
typedef __attribute__((ext_vector_type(4))) float f32x4;
typedef __attribute__((ext_vector_type(2))) unsigned int u32x2;

static __device__ __forceinline__ float bf2f(short s) {
  unsigned u = ((unsigned)(unsigned short)s) << 16;
  float f; __builtin_memcpy(&f, &u, 4); return f;
}
static __device__ __forceinline__ short f2bf(float f) {
  unsigned u; __builtin_memcpy(&u, &f, 4);
  unsigned r = u + 0x7FFFu + ((u >> 16) & 1u);
  return (short)(r >> 16);
}
static __device__ __forceinline__ float wredsum64(float v) {
#pragma unroll
  for (int m = 32; m >= 1; m >>= 1) v += __shfl_xor(v, m);
  return v;
}

#if defined(__has_builtin)
#if __has_builtin(__builtin_amdgcn_global_load_lds)
#define HAVE_GLLDS 1
#endif
#endif

static __device__ __forceinline__ void gl_lds16(const short* g, short* l) {
#ifdef HAVE_GLLDS
  __builtin_amdgcn_global_load_lds(
      (const __attribute__((address_space(1))) void*)g,
      (__attribute__((address_space(3))) void*)l, 16, 0, 0);
#else
  // fallback: manual copy (lane writes its own 16B at l + lane*8 shorts)
  int lane = threadIdx.x & 63;
  *(bf16x8*)(l + lane * 8) = *(const bf16x8*)g;
#endif
}

// ---------------------------------------------------------------- pool + LN
__global__ __launch_bounds__(256) void pool_ln_kernel(
    const float* __restrict__ x,
    const float* __restrict__ wq9, const float* __restrict__ wk9, const float* __restrict__ wv9,
    const float* __restrict__ gq, const float* __restrict__ bq,
    const float* __restrict__ gk, const float* __restrict__ bk,
    const float* __restrict__ gv, const float* __restrict__ bv,
    short* __restrict__ Pq, short* __restrict__ Pk, short* __restrict__ Pv)
{
  int blk = blockIdx.x;             // b*NTOK + n
  int b = blk / NTOK, n = blk % NTOK;
  int wid = threadIdx.x >> 6, lane = threadIdx.x & 63;
  int c = lane;
  for (int hs = 0; hs < 3; ++hs) {
    int h = wid + 4 * hs;
    float aq, ak, av;
    if (n == 0) {
      float v0 = x[((size_t)b * NIN + 0) * DMODEL + h * HEAD_DIM + c];
      aq = ak = av = v0;
    } else {
      int s = n - 1;
      int i = s / PHDIM, j = s % PHDIM;
      aq = ak = av = 0.f;
#pragma unroll
      for (int di = 0; di < 3; ++di) {
        int ii = 2 * i - 1 + di;
        if (ii < 0 || ii >= HWDIM) continue;
#pragma unroll
        for (int dj = 0; dj < 3; ++dj) {
          int jj = 2 * j - 1 + dj;
          if (jj < 0 || jj >= HWDIM) continue;
          float xin = x[((size_t)b * NIN + 1 + ii * HWDIM + jj) * DMODEL + h * HEAD_DIM + c];
          int tap = di * 3 + dj;
          aq += wq9[c * 9 + tap] * xin;
          ak += wk9[c * 9 + tap] * xin;
          av += wv9[c * 9 + tap] * xin;
        }
      }
    }
    size_t oo = ((size_t)b * NTOK + n) * DMODEL + h * HEAD_DIM + c;
    {
      float mn = wredsum64(aq) * (1.f / 64.f);
      float d = aq - mn;
      float vv = wredsum64(d * d) * (1.f / 64.f);
      Pq[oo] = f2bf(d * rsqrtf(vv + 1e-5f) * gq[c] + bq[c]);
    }
    {
      float mn = wredsum64(ak) * (1.f / 64.f);
      float d = ak - mn;
      float vv = wredsum64(d * d) * (1.f / 64.f);
      Pk[oo] = f2bf(d * rsqrtf(vv + 1e-5f) * gk[c] + bk[c]);
    }
    {
      float mn = wredsum64(av) * (1.f / 64.f);
      float d = av - mn;
      float vv = wredsum64(d * d) * (1.f / 64.f);
      Pv[oo] = f2bf(d * rsqrtf(vv + 1e-5f) * gv[c] + bv[c]);
    }
  }
}

// ------------------------------------------------- weight transpose fp32->bf16
__global__ __launch_bounds__(256) void trans_kernel(
    const float* __restrict__ s0, const float* __restrict__ s1,
    const float* __restrict__ s2, const float* __restrict__ s3,
    short* __restrict__ d0, short* __restrict__ d1,
    short* __restrict__ d2, short* __restrict__ d3)
{
  __shared__ float tile[32][33];
  int z = blockIdx.z;
  const float* s = (z == 0) ? s0 : (z == 1) ? s1 : (z == 2) ? s2 : s3;
  short* d = (z == 0) ? d0 : (z == 1) ? d1 : (z == 2) ? d2 : d3;
  int k0 = blockIdx.x * 32, n0 = blockIdx.y * 32;
  int tx = threadIdx.x, ty = threadIdx.y;   // 32 x 8
#pragma unroll
  for (int jj = 0; jj < 4; ++jj)
    tile[ty + jj * 8][tx] = s[(size_t)(k0 + ty + jj * 8) * DMODEL + n0 + tx];
  __syncthreads();
#pragma unroll
  for (int jj = 0; jj < 4; ++jj)
    d[(size_t)(n0 + ty + jj * 8) * DMODEL + k0 + tx] = f2bf(tile[tx][ty + jj * 8]);
}

// ------------------------------------------------------------- bf16 MFMA GEMM
// m97-style: global_load_lds staging, linear LDS [128][32]
// C[M,768] = A[M,768] @ Bt[768,768]^T + bias
// mode0: fp32 row-major out; mode1: bf16 out in (B,12,785,64) layout
__global__ __launch_bounds__(256) void gemm2_kernel(
    const short* __restrict__ A, const short* __restrict__ Bt,
    const float* __restrict__ bias, void* __restrict__ outp,
    int M, int mode)
{
  const int K = DMODEL;
  __shared__ short As[128 * 32];
  __shared__ short Bs[128 * 32];
  int tid = threadIdx.x;
  int wid = tid >> 6, lane = tid & 63;
  int lg = lane >> 4, lq = lane & 15;
  int wm = wid >> 1, wn = wid & 1;
  int rowbase = blockIdx.x * 128;
  int colbase = blockIdx.y * 128;

  f32x4 acc[4][4];
#pragma unroll
  for (int i = 0; i < 4; ++i)
#pragma unroll
    for (int j = 0; j < 4; ++j) acc[i][j] = (f32x4){0.f, 0.f, 0.f, 0.f};

  int srow = tid >> 2;            // 0..63
  int scol = (tid & 3) * 8;
  int ar0 = min(rowbase + srow, M - 1);
  int ar1 = min(rowbase + 64 + srow, M - 1);
  const short* Ag0 = A + (size_t)ar0 * K + scol;
  const short* Ag1 = A + (size_t)ar1 * K + scol;
  const short* Bg0 = Bt + (size_t)(colbase + srow) * K + scol;
  const short* Bg1 = Bt + (size_t)(colbase + 64 + srow) * K + scol;
  short* AsW0 = As + wid * 512;          // rows 16w..16w+15
  short* AsW1 = As + 2048 + wid * 512;   // rows 64+16w..
  short* BsW0 = Bs + wid * 512;
  short* BsW1 = Bs + 2048 + wid * 512;

  for (int kt = 0; kt < K; kt += 32) {
    __syncthreads();
    gl_lds16(Ag0 + kt, AsW0);
    gl_lds16(Ag1 + kt, AsW1);
    gl_lds16(Bg0 + kt, BsW0);
    gl_lds16(Bg1 + kt, BsW1);
    __syncthreads();
    bf16x8 aFrag[4], bFrag[4];
#pragma unroll
    for (int mi = 0; mi < 4; ++mi)
      aFrag[mi] = *(const bf16x8*)&As[(wm * 64 + mi * 16 + lq) * 32 + lg * 8];
#pragma unroll
    for (int ni = 0; ni < 4; ++ni)
      bFrag[ni] = *(const bf16x8*)&Bs[(wn * 64 + ni * 16 + lq) * 32 + lg * 8];
#pragma unroll
    for (int mi = 0; mi < 4; ++mi)
#pragma unroll
      for (int ni = 0; ni < 4; ++ni)
        acc[mi][ni] = __builtin_amdgcn_mfma_f32_16x16x32_bf16(aFrag[mi], bFrag[ni], acc[mi][ni], 0, 0, 0);
  }

#pragma unroll
  for (int mi = 0; mi < 4; ++mi) {
    int rowq = rowbase + wm * 64 + mi * 16 + lg * 4;
#pragma unroll
    for (int r = 0; r < 4; ++r) {
      int row = rowq + r;
      if (row < M) {
        int bb = row / NTOK;
        int nn = row - bb * NTOK;
#pragma unroll
        for (int ni = 0; ni < 4; ++ni) {
          int col = colbase + wn * 64 + ni * 16 + lq;
          float v = acc[mi][ni][r] + bias[col];
          if (mode == 0) {
            ((float*)outp)[(size_t)row * DMODEL + col] = v;
          } else {
            ((short*)outp)[(((size_t)(bb * NUM_HEADS + (col >> 6)) * NTOK + nn) << 6) + (col & 63)] = f2bf(v);
          }
        }
      }
    }
  }
}

// -------------------------------------------------------- rel-pos bias tables
__global__ __launch_bounds__(256) void relbias_kernel(
    const short* __restrict__ qh, const float* __restrict__ rph,
    const float* __restrict__ rpw, float* __restrict__ RelH, float* __restrict__ RelW)
{
  int line = blockIdx.x;   // i (mode0) or j (mode1)
  int bh = blockIdx.y;
  int mode = blockIdx.z;
  __shared__ __align__(16) float qt_s[28 * 68];
  __shared__ __align__(16) float rt_s[28 * 68];
  int tid = threadIdx.x;
  const float* rp = (mode == 0) ? rph : rpw;
  for (int idx = tid; idx < 28 * 64; idx += 256) {
    int rr = idx >> 6, c = idx & 63;
    int qi = (mode == 0) ? (1 + line * PHDIM + rr) : (1 + rr * PHDIM + line);
    qt_s[rr * 68 + c] = bf2f(qh[((size_t)bh * NTOK + qi) * HEAD_DIM + c]);
    rt_s[rr * 68 + c] = rp[(line - rr + 27) * HEAD_DIM + c];
  }
  __syncthreads();
  for (int o = tid; o < 784; o += 256) {
    int rr = o / PHDIM, kk = o % PHDIM;
    const f32x4* qa = (const f32x4*)&qt_s[rr * 68];
    const f32x4* ra = (const f32x4*)&rt_s[kk * 68];
    f32x4 a4 = (f32x4){0.f, 0.f, 0.f, 0.f};
#pragma unroll
    for (int i = 0; i < 16; ++i) a4 += qa[i] * ra[i];
    float s = a4[0] + a4[1] + a4[2] + a4[3];
    if (mode == 0) {
      int qrow = line * PHDIM + rr;
      RelH[((size_t)bh * 784 + qrow) * PHDIM + kk] = s;
    } else {
      int qrow = rr * PHDIM + line;
      RelW[((size_t)bh * 784 + qrow) * PHDIM + kk] = s;
    }
  }
}

// ------------------------------------------------------------ flash attention
// swapped QK^T: s = mfma(K,Q) -> lane holds 16 S values for one q-row.
__global__ __launch_bounds__(256) void flash2_kernel(
    const short* __restrict__ qh, const short* __restrict__ kh, const short* __restrict__ vh,
    const float* __restrict__ RelH, const float* __restrict__ RelW,
    short* __restrict__ Afin)
{
  int id = blockIdx.x;
  int slot = id >> 3;
  int bh = (id & 7) * 24 + slot / 13;   // all 13 q-tiles of a bh on one XCD
  int qt = slot - (slot / 13) * 13;
  int qbase = qt * 64;
  int tid = threadIdx.x, wid = tid >> 6, lane = tid & 63;
  int lg = lane >> 4, lq = lane & 15;

  __shared__ __align__(16) float relh[64 * 28];
  __shared__ __align__(16) float relw[64 * 28];
  __shared__ __align__(16) short vt[64 * 64];       // swizzled V^T [d][key]
  __shared__ __align__(16) short pbuf[4][16 * 64];  // per-wave [q][key] swizzled
  __shared__ __align__(16) float axl[4][16];

  for (int idx = tid; idx < 64 * 28; idx += 256) {
    int ql = idx / 28, kk = idx - ql * 28;
    int qi = qbase + ql;
    float rh = 0.f, rw = 0.f;
    if (qi >= 1 && qi < NTOK) {
      rh = RelH[((size_t)bh * 784 + (qi - 1)) * PHDIM + kk];
      rw = RelW[((size_t)bh * 784 + (qi - 1)) * PHDIM + kk];
    }
    relh[idx] = rh; relw[idx] = rw;
  }

  int qi0 = qbase + wid * 16 + lq;
  int qiq = min(qi0, NTOK - 1);
  const short* qrow = qh + ((size_t)bh * NTOK + qiq) * HEAD_DIM;
  bf16x8 bq0 = *(const bf16x8*)(qrow + lg * 8);
  bf16x8 bq1 = *(const bf16x8*)(qrow + 32 + lg * 8);

  float m_l = -3e30f, l_l = 0.f;
  f32x4 acc[4];
#pragma unroll
  for (int ch = 0; ch < 4; ++ch) acc[ch] = (f32x4){0.f, 0.f, 0.f, 0.f};

  const float scale = 0.125f;
  int q_local = wid * 16 + lq;

  for (int step = 0; step < 13; ++step) {
    int kvb = step * 64;
    __syncthreads();
    { // stage V^T (swizzled): lane = key, wave covers d range wid*16..+15
      int kv = min(kvb + lane, NTOK - 1);
      const short* vr = vh + ((size_t)bh * NTOK + kv) * HEAD_DIM + wid * 16;
      bf16x8 v0 = *(const bf16x8*)vr;
      bf16x8 v1 = *(const bf16x8*)(vr + 8);
#pragma unroll
      for (int e = 0; e < 8; ++e) {
        int d = wid * 16 + e;
        vt[((d * 128 + lane * 2) ^ ((d & 7) << 4)) >> 1] = v0[e];
      }
#pragma unroll
      for (int e = 0; e < 8; ++e) {
        int d = wid * 16 + 8 + e;
        vt[((d * 128 + lane * 2) ^ ((d & 7) << 4)) >> 1] = v1[e];
      }
    }
    __syncthreads();

    float p[16];
#pragma unroll
    for (int kt = 0; kt < 4; ++kt) {
      int krow_i = min(kvb + kt * 16 + lq, NTOK - 1);
      const short* krow = kh + ((size_t)bh * NTOK + krow_i) * HEAD_DIM;
      bf16x8 aK0 = *(const bf16x8*)(krow + lg * 8);
      bf16x8 aK1 = *(const bf16x8*)(krow + 32 + lg * 8);
      f32x4 s = (f32x4){0.f, 0.f, 0.f, 0.f};
      s = __builtin_amdgcn_mfma_f32_16x16x32_bf16(aK0, bq0, s, 0, 0, 0);
      s = __builtin_amdgcn_mfma_f32_16x16x32_bf16(aK1, bq1, s, 0, 0, 0);
#pragma unroll
      for (int r = 0; r < 4; ++r) {
        int key = kvb + kt * 16 + lg * 4 + r;
        float v = s[r] * scale;
        if (key >= 1 && key < NTOK) {
          int km1 = key - 1;
          int ki = km1 / PHDIM, kj = km1 - ki * PHDIM;
          v += relh[q_local * 28 + ki] + relw[q_local * 28 + kj];
        }
        if (key >= NTOK) v = -3e30f;
        p[kt * 4 + r] = v;
      }
    }

    // ---- softmax (row is lane-local; cross 4 lane-groups via 2 shfls)
    float pm = p[0];
#pragma unroll
    for (int i = 1; i < 16; ++i) pm = fmaxf(pm, p[i]);
    pm = fmaxf(pm, __shfl_xor(pm, 16));
    pm = fmaxf(pm, __shfl_xor(pm, 32));
    if (!__all(pm - m_l <= 8.f)) {   // defer-rescale (T13)
      float mnew = fmaxf(m_l, pm);
      float alpha = __expf(m_l - mnew);
      m_l = mnew;
      l_l *= alpha;
      if (lg == 0) axl[wid][lq] = alpha;
      f32x4 av = *(const f32x4*)&axl[wid][lg * 4];
#pragma unroll
      for (int ch = 0; ch < 4; ++ch)
#pragma unroll
        for (int r = 0; r < 4; ++r) acc[ch][r] *= av[r];
    }
    float ps = 0.f;
#pragma unroll
    for (int i = 0; i < 16; ++i) { p[i] = __expf(p[i] - m_l); ps += p[i]; }
    ps += __shfl_xor(ps, 16);
    ps += __shfl_xor(ps, 32);
    l_l += ps;

    // ---- pack P -> per-wave LDS (b64 writes)
    short* pw = (short*)pbuf[wid];
#pragma unroll
    for (int kt = 0; kt < 4; ++kt) {
      unsigned lo = ((unsigned)(unsigned short)f2bf(p[kt * 4 + 0])) |
                    ((unsigned)(unsigned short)f2bf(p[kt * 4 + 1]) << 16);
      unsigned hi = ((unsigned)(unsigned short)f2bf(p[kt * 4 + 2])) |
                    ((unsigned)(unsigned short)f2bf(p[kt * 4 + 3]) << 16);
      int byte = (lq * 128 + (kt * 16 + lg * 4) * 2) ^ ((lq & 7) << 4);
      u32x2 pk; pk[0] = lo; pk[1] = hi;
      *(u32x2*)((char*)pw + byte) = pk;
    }
    // ---- PV
#pragma unroll
    for (int kc = 0; kc < 2; ++kc) {
      int pbyte = (lq * 128 + kc * 64 + lg * 16) ^ ((lq & 7) << 4);
      bf16x8 pa = *(const bf16x8*)((char*)pw + pbyte);
#pragma unroll
      for (int ch = 0; ch < 4; ++ch) {
        int d = ch * 16 + lq;
        int vbyte = (d * 128 + kc * 64 + lg * 16) ^ ((d & 7) << 4);
        bf16x8 bv = *(const bf16x8*)((char*)vt + vbyte);
        acc[ch] = __builtin_amdgcn_mfma_f32_16x16x32_bf16(pa, bv, acc[ch], 0, 0, 0);
      }
    }
  }

  // epilogue: broadcast lsum to PV layout, add q residual, write per-head concat
  if (lg == 0) axl[wid][lq] = l_l;
  f32x4 lv = *(const f32x4*)&axl[wid][lg * 4];
  int b = bh / NUM_HEADS, h = bh - b * NUM_HEADS;
#pragma unroll
  for (int r = 0; r < 4; ++r) {
    int qi = qbase + wid * 16 + lg * 4 + r;
    if (qi < NTOK) {
      float inv = 1.f / lv[r];
#pragma unroll
      for (int ch = 0; ch < 4; ++ch) {
        int d = ch * 16 + lq;
        float o = acc[ch][r] * inv + bf2f(qh[((size_t)bh * NTOK + qi) * HEAD_DIM + d]);
        Afin[((size_t)b * NTOK + qi) * DMODEL + h * HEAD_DIM + d] = f2bf(o);
      }
    }
  }
}

// ------------------------------------------------------------------- launcher
extern "C" void kernel_launch(void* const* d_in, const int* in_sizes, int n_in,
                              void* d_out, int out_size, void* d_ws, size_t ws_size,
                              hipStream_t stream)
{
  (void)in_sizes; (void)n_in; (void)out_size; (void)ws_size;
  const float* x   = (const float*)d_in[0];
  const float* pqw = (const float*)d_in[1];
  const float* pkw = (const float*)d_in[2];
  const float* pvw = (const float*)d_in[3];
  const float* gq  = (const float*)d_in[4];
  const float* bq_ = (const float*)d_in[5];
  const float* gk  = (const float*)d_in[6];
  const float* bk_ = (const float*)d_in[7];
  const float* gv  = (const float*)d_in[8];
  const float* bv_ = (const float*)d_in[9];
  const float* wq  = (const float*)d_in[10];
  const float* bqp = (const float*)d_in[11];
  const float* wk  = (const float*)d_in[12];
  const float* bkp = (const float*)d_in[13];
  const float* wv  = (const float*)d_in[14];
  const float* bvp = (const float*)d_in[15];
  const float* wp  = (const float*)d_in[16];
  const float* bpp = (const float*)d_in[17];
  const float* rph = (const float*)d_in[18];
  const float* rpw = (const float*)d_in[19];

  char* ws = (char*)d_ws;
  size_t off = 0;
  auto alloc = [&](size_t bytes) -> void* {
    void* p = ws + off; off += (bytes + 255) & ~(size_t)255; return p;
  };
  const size_t MROWS = (size_t)BATCH * NTOK;   // 12560
  short* Pq  = (short*)alloc(MROWS * DMODEL * 2);
  short* Pk  = (short*)alloc(MROWS * DMODEL * 2);
  short* Pv  = (short*)alloc(MROWS * DMODEL * 2);
  short* WqT = (short*)alloc((size_t)DMODEL * DMODEL * 2);
  short* WkT = (short*)alloc((size_t)DMODEL * DMODEL * 2);
  short* WvT = (short*)alloc((size_t)DMODEL * DMODEL * 2);
  short* WpT = (short*)alloc((size_t)DMODEL * DMODEL * 2);
  short* qhd = (short*)alloc(MROWS * DMODEL * 2 + 4096);
  short* khd = (short*)alloc(MROWS * DMODEL * 2 + 4096);
  short* vhd = (short*)alloc(MROWS * DMODEL * 2 + 4096);
  float* RelH = (float*)alloc((size_t)BHCNT * 784 * 28 * 4);
  float* RelW = (float*)alloc((size_t)BHCNT * 784 * 28 * 4);
  short* Afin = (short*)alloc(MROWS * DMODEL * 2);

  pool_ln_kernel<<<dim3(BATCH * NTOK), 256, 0, stream>>>(
      x, pqw, pkw, pvw, gq, bq_, gk, bk_, gv, bv_, Pq, Pk, Pv);
  trans_kernel<<<dim3(24, 24, 4), dim3(32, 8), 0, stream>>>(
      wq, wk, wv, wp, WqT, WkT, WvT, WpT);
  dim3 gg(99, 6);
  gemm2_kernel<<<gg, 256, 0, stream>>>(Pq, WqT, bqp, qhd, (int)MROWS, 1);
  gemm2_kernel<<<gg, 256, 0, stream>>>(Pk, WkT, bkp, khd, (int)MROWS, 1);
  gemm2_kernel<<<gg, 256, 0, stream>>>(Pv, WvT, bvp, vhd, (int)MROWS, 1);
  relbias_kernel<<<dim3(28, BHCNT, 2), 256, 0, stream>>>(qhd, rph, rpw, RelH, RelW);
  flash2_kernel<<<dim3(2496), 256, 0, stream>>>(qhd, khd, vhd, RelH, RelW, Afin);
  gemm2_kernel<<<gg, 256, 0, stream>>>(Afin, WpT, bpp, d_out, (int)MROWS, 0);
}

// Round 3
// 473.283 us; speedup vs baseline: 1.5997x; 1.2562x over previous
//
#include <hip/hip_runtime.h>
#include <stdint.h>

#define NUM_HEADS 12
#define HEAD_DIM  64
#define HWDIM     56
#define PHDIM     28
#define NTOK      785     // 28*28+1
#define NIN       3137    // 56*56+1
#define BATCH     16
#define DMODEL    768
#define BHCNT     192     // BATCH*NUM_HEADS

typedef __attribute__((ext_vector_type(8))) short bf16x8;
typedef __attribute__((ext_vector_type(4))) short s16x4;
typedef __attribute__((ext_vector_type(4))) float f32x4;
typedef __attribute__((ext_vector_type(2))) unsigned int u32x2;

static __device__ __forceinline__ float bf2f(short s) {
  unsigned u = ((unsigned)(unsigned short)s) << 16;
  float f; __builtin_memcpy(&f, &u, 4); return f;
}
static __device__ __forceinline__ short f2bf(float f) {
  unsigned u; __builtin_memcpy(&u, &f, 4);
  unsigned r = u + 0x7FFFu + ((u >> 16) & 1u);
  return (short)(r >> 16);
}

#if defined(__has_builtin)
#if __has_builtin(__builtin_amdgcn_global_load_lds)
#define HAVE_GLLDS 1
#endif
#endif

static __device__ __forceinline__ void gl_lds16(const short* g, short* l) {
#ifdef HAVE_GLLDS
  __builtin_amdgcn_global_load_lds(
      (const __attribute__((address_space(1))) void*)g,
      (__attribute__((address_space(3))) void*)l, 16, 0, 0);
#else
  int lane = threadIdx.x & 63;
  *(bf16x8*)(l + lane * 8) = *(const bf16x8*)g;
#endif
}

// ---------------------------------------------------------------- pool + LN
// block = 192 threads (12 heads x 16 lanes), handles 4 consecutive tokens.
// thread covers 4 contiguous channels -> f32x4 loads; LN reduce over 16 lanes.
__global__ __launch_bounds__(192) void pool_ln_kernel(
    const float* __restrict__ x,
    const float* __restrict__ wq9, const float* __restrict__ wk9, const float* __restrict__ wv9,
    const float* __restrict__ gq, const float* __restrict__ bq,
    const float* __restrict__ gk, const float* __restrict__ bk,
    const float* __restrict__ gv, const float* __restrict__ bv,
    short* __restrict__ Pq, short* __restrict__ Pk, short* __restrict__ Pv)
{
  __shared__ __align__(16) float wt_s[3][9][64];   // [conv][tap][c]
  int tid = threadIdx.x;
  int blk = blockIdx.x;
  int b = blk / 197;
  int n0 = (blk - b * 197) * 4;

  // stage conv weights (transpose [c][tap] -> [tap][c]); uniform, L2-hot
  for (int idx = tid; idx < 3 * 576; idx += 192) {
    int conv = idx / 576, rem = idx - conv * 576;
    int c = rem / 9, tap = rem - c * 9;
    const float* wsrc = (conv == 0) ? wq9 : (conv == 1) ? wk9 : wv9;
    wt_s[conv][tap][c] = wsrc[c * 9 + tap];
  }
  __syncthreads();

  int ch0 = tid * 4;          // global channel (0..764)
  int c4 = ch0 & 63;          // channel within head
  f32x4 g_q = *(const f32x4*)&gq[c4], b_q = *(const f32x4*)&bq[c4];
  f32x4 g_k = *(const f32x4*)&gk[c4], b_k = *(const f32x4*)&bk[c4];
  f32x4 g_v = *(const f32x4*)&gv[c4], b_v = *(const f32x4*)&bv[c4];

  for (int tt = 0; tt < 4; ++tt) {
    int n = n0 + tt;
    if (n >= NTOK) break;
    f32x4 aq = (f32x4){0.f, 0.f, 0.f, 0.f}, ak = aq, av = aq;
    if (n == 0) {
      f32x4 x4 = *(const f32x4*)&x[((size_t)b * NIN) * DMODEL + ch0];
      aq = ak = av = x4;
    } else {
      int s = n - 1;
      int i = s / PHDIM, j = s - i * PHDIM;
#pragma unroll
      for (int di = 0; di < 3; ++di) {
        int ii = 2 * i - 1 + di;
        if (ii < 0 || ii >= HWDIM) continue;
#pragma unroll
        for (int dj = 0; dj < 3; ++dj) {
          int jj = 2 * j - 1 + dj;
          if (jj < 0 || jj >= HWDIM) continue;
          f32x4 x4 = *(const f32x4*)&x[((size_t)b * NIN + 1 + ii * HWDIM + jj) * DMODEL + ch0];
          int tap = di * 3 + dj;
          f32x4 w0 = *(const f32x4*)&wt_s[0][tap][c4];
          f32x4 w1 = *(const f32x4*)&wt_s[1][tap][c4];
          f32x4 w2 = *(const f32x4*)&wt_s[2][tap][c4];
          aq += w0 * x4; ak += w1 * x4; av += w2 * x4;
        }
      }
    }
    size_t obase = ((size_t)b * NTOK + n) * DMODEL + ch0;
    // ---- LN over 64 channels = 16 lanes x 4 elems
    {
      float sm = aq[0] + aq[1] + aq[2] + aq[3];
#pragma unroll
      for (int m = 1; m < 16; m <<= 1) sm += __shfl_xor(sm, m);
      float mn = sm * (1.f / 64.f);
      f32x4 d = aq - mn;
      float vs = d[0]*d[0] + d[1]*d[1] + d[2]*d[2] + d[3]*d[3];
#pragma unroll
      for (int m = 1; m < 16; m <<= 1) vs += __shfl_xor(vs, m);
      float rs = rsqrtf(vs * (1.f / 64.f) + 1e-5f);
      s16x4 o;
#pragma unroll
      for (int e = 0; e < 4; ++e) o[e] = f2bf(d[e] * rs * g_q[e] + b_q[e]);
      *(s16x4*)&Pq[obase] = o;
    }
    {
      float sm = ak[0] + ak[1] + ak[2] + ak[3];
#pragma unroll
      for (int m = 1; m < 16; m <<= 1) sm += __shfl_xor(sm, m);
      float mn = sm * (1.f / 64.f);
      f32x4 d = ak - mn;
      float vs = d[0]*d[0] + d[1]*d[1] + d[2]*d[2] + d[3]*d[3];
#pragma unroll
      for (int m = 1; m < 16; m <<= 1) vs += __shfl_xor(vs, m);
      float rs = rsqrtf(vs * (1.f / 64.f) + 1e-5f);
      s16x4 o;
#pragma unroll
      for (int e = 0; e < 4; ++e) o[e] = f2bf(d[e] * rs * g_k[e] + b_k[e]);
      *(s16x4*)&Pk[obase] = o;
    }
    {
      float sm = av[0] + av[1] + av[2] + av[3];
#pragma unroll
      for (int m = 1; m < 16; m <<= 1) sm += __shfl_xor(sm, m);
      float mn = sm * (1.f / 64.f);
      f32x4 d = av - mn;
      float vs = d[0]*d[0] + d[1]*d[1] + d[2]*d[2] + d[3]*d[3];
#pragma unroll
      for (int m = 1; m < 16; m <<= 1) vs += __shfl_xor(vs, m);
      float rs = rsqrtf(vs * (1.f / 64.f) + 1e-5f);
      s16x4 o;
#pragma unroll
      for (int e = 0; e < 4; ++e) o[e] = f2bf(d[e] * rs * g_v[e] + b_v[e]);
      *(s16x4*)&Pv[obase] = o;
    }
  }
}

// ------------------------------------------------- weight transpose fp32->bf16
__global__ __launch_bounds__(256) void trans_kernel(
    const float* __restrict__ s0, const float* __restrict__ s1,
    const float* __restrict__ s2, const float* __restrict__ s3,
    short* __restrict__ d0, short* __restrict__ d1,
    short* __restrict__ d2, short* __restrict__ d3)
{
  __shared__ float tile[32][33];
  int z = blockIdx.z;
  const float* s = (z == 0) ? s0 : (z == 1) ? s1 : (z == 2) ? s2 : s3;
  short* d = (z == 0) ? d0 : (z == 1) ? d1 : (z == 2) ? d2 : d3;
  int k0 = blockIdx.x * 32, n0 = blockIdx.y * 32;
  int tx = threadIdx.x, ty = threadIdx.y;   // 32 x 8
#pragma unroll
  for (int jj = 0; jj < 4; ++jj)
    tile[ty + jj * 8][tx] = s[(size_t)(k0 + ty + jj * 8) * DMODEL + n0 + tx];
  __syncthreads();
#pragma unroll
  for (int jj = 0; jj < 4; ++jj)
    d[(size_t)(n0 + ty + jj * 8) * DMODEL + k0 + tx] = f2bf(tile[tx][ty + jj * 8]);
}

// ------------------------------------------------------------- bf16 MFMA GEMM
// m97-style: global_load_lds staging, linear LDS [128][32]
__global__ __launch_bounds__(256) void gemm2_kernel(
    const short* __restrict__ A, const short* __restrict__ Bt,
    const float* __restrict__ bias, void* __restrict__ outp,
    int M, int mode)
{
  const int K = DMODEL;
  __shared__ short As[128 * 32];
  __shared__ short Bs[128 * 32];
  int tid = threadIdx.x;
  int wid = tid >> 6, lane = tid & 63;
  int lg = lane >> 4, lq = lane & 15;
  int wm = wid >> 1, wn = wid & 1;
  int rowbase = blockIdx.x * 128;
  int colbase = blockIdx.y * 128;

  f32x4 acc[4][4];
#pragma unroll
  for (int i = 0; i < 4; ++i)
#pragma unroll
    for (int j = 0; j < 4; ++j) acc[i][j] = (f32x4){0.f, 0.f, 0.f, 0.f};

  int srow = tid >> 2;            // 0..63
  int scol = (tid & 3) * 8;
  int ar0 = min(rowbase + srow, M - 1);
  int ar1 = min(rowbase + 64 + srow, M - 1);
  const short* Ag0 = A + (size_t)ar0 * K + scol;
  const short* Ag1 = A + (size_t)ar1 * K + scol;
  const short* Bg0 = Bt + (size_t)(colbase + srow) * K + scol;
  const short* Bg1 = Bt + (size_t)(colbase + 64 + srow) * K + scol;
  short* AsW0 = As + wid * 512;
  short* AsW1 = As + 2048 + wid * 512;
  short* BsW0 = Bs + wid * 512;
  short* BsW1 = Bs + 2048 + wid * 512;

  for (int kt = 0; kt < K; kt += 32) {
    __syncthreads();
    gl_lds16(Ag0 + kt, AsW0);
    gl_lds16(Ag1 + kt, AsW1);
    gl_lds16(Bg0 + kt, BsW0);
    gl_lds16(Bg1 + kt, BsW1);
    __syncthreads();
    bf16x8 aFrag[4], bFrag[4];
#pragma unroll
    for (int mi = 0; mi < 4; ++mi)
      aFrag[mi] = *(const bf16x8*)&As[(wm * 64 + mi * 16 + lq) * 32 + lg * 8];
#pragma unroll
    for (int ni = 0; ni < 4; ++ni)
      bFrag[ni] = *(const bf16x8*)&Bs[(wn * 64 + ni * 16 + lq) * 32 + lg * 8];
#pragma unroll
    for (int mi = 0; mi < 4; ++mi)
#pragma unroll
      for (int ni = 0; ni < 4; ++ni)
        acc[mi][ni] = __builtin_amdgcn_mfma_f32_16x16x32_bf16(aFrag[mi], bFrag[ni], acc[mi][ni], 0, 0, 0);
  }

#pragma unroll
  for (int mi = 0; mi < 4; ++mi) {
    int rowq = rowbase + wm * 64 + mi * 16 + lg * 4;
#pragma unroll
    for (int r = 0; r < 4; ++r) {
      int row = rowq + r;
      if (row < M) {
        int bb = row / NTOK;
        int nn = row - bb * NTOK;
#pragma unroll
        for (int ni = 0; ni < 4; ++ni) {
          int col = colbase + wn * 64 + ni * 16 + lq;
          float v = acc[mi][ni][r] + bias[col];
          if (mode == 0) {
            ((float*)outp)[(size_t)row * DMODEL + col] = v;
          } else {
            ((short*)outp)[(((size_t)(bb * NUM_HEADS + (col >> 6)) * NTOK + nn) << 6) + (col & 63)] = f2bf(v);
          }
        }
      }
    }
  }
}

// -------------------------------------------------------- rel-pos bias tables
__global__ __launch_bounds__(256) void relbias_kernel(
    const short* __restrict__ qh, const float* __restrict__ rph,
    const float* __restrict__ rpw, float* __restrict__ RelH, float* __restrict__ RelW)
{
  int line = blockIdx.x;   // i (mode0) or j (mode1)
  int bh = blockIdx.y;
  int mode = blockIdx.z;
  __shared__ __align__(16) float qt_s[28 * 68];
  __shared__ __align__(16) float rt_s[28 * 68];
  int tid = threadIdx.x;
  const float* rp = (mode == 0) ? rph : rpw;
  for (int idx = tid; idx < 28 * 64; idx += 256) {
    int rr = idx >> 6, c = idx & 63;
    int qi = (mode == 0) ? (1 + line * PHDIM + rr) : (1 + rr * PHDIM + line);
    qt_s[rr * 68 + c] = bf2f(qh[((size_t)bh * NTOK + qi) * HEAD_DIM + c]);
    rt_s[rr * 68 + c] = rp[(line - rr + 27) * HEAD_DIM + c];
  }
  __syncthreads();
  for (int o = tid; o < 784; o += 256) {
    int rr = o / PHDIM, kk = o % PHDIM;
    const f32x4* qa = (const f32x4*)&qt_s[rr * 68];
    const f32x4* ra = (const f32x4*)&rt_s[kk * 68];
    f32x4 a4 = (f32x4){0.f, 0.f, 0.f, 0.f};
#pragma unroll
    for (int i = 0; i < 16; ++i) a4 += qa[i] * ra[i];
    float s = a4[0] + a4[1] + a4[2] + a4[3];
    if (mode == 0) {
      int qrow = line * PHDIM + rr;
      RelH[((size_t)bh * 784 + qrow) * PHDIM + kk] = s;
    } else {
      int qrow = rr * PHDIM + line;
      RelW[((size_t)bh * 784 + qrow) * PHDIM + kk] = s;
    }
  }
}

// ------------------------------------------------------------ flash attention
__global__ __launch_bounds__(256) void flash2_kernel(
    const short* __restrict__ qh, const short* __restrict__ kh, const short* __restrict__ vh,
    const float* __restrict__ RelH, const float* __restrict__ RelW,
    short* __restrict__ Afin)
{
  int id = blockIdx.x;
  int slot = id >> 3;
  int bh = (id & 7) * 24 + slot / 13;   // all 13 q-tiles of a bh on one XCD
  int qt = slot - (slot / 13) * 13;
  int qbase = qt * 64;
  int tid = threadIdx.x, wid = tid >> 6, lane = tid & 63;
  int lg = lane >> 4, lq = lane & 15;

  __shared__ __align__(16) float relh[64 * 28];
  __shared__ __align__(16) float relw[64 * 28];
  __shared__ __align__(16) short vt[64 * 64];
  __shared__ __align__(16) short pbuf[4][16 * 64];
  __shared__ __align__(16) float axl[4][16];

  for (int idx = tid; idx < 64 * 28; idx += 256) {
    int ql = idx / 28, kk = idx - ql * 28;
    int qi = qbase + ql;
    float rh = 0.f, rw = 0.f;
    if (qi >= 1 && qi < NTOK) {
      rh = RelH[((size_t)bh * 784 + (qi - 1)) * PHDIM + kk];
      rw = RelW[((size_t)bh * 784 + (qi - 1)) * PHDIM + kk];
    }
    relh[idx] = rh; relw[idx] = rw;
  }

  int qi0 = qbase + wid * 16 + lq;
  int qiq = min(qi0, NTOK - 1);
  const short* qrow = qh + ((size_t)bh * NTOK + qiq) * HEAD_DIM;
  bf16x8 bq0 = *(const bf16x8*)(qrow + lg * 8);
  bf16x8 bq1 = *(const bf16x8*)(qrow + 32 + lg * 8);

  float m_l = -3e30f, l_l = 0.f;
  f32x4 acc[4];
#pragma unroll
  for (int ch = 0; ch < 4; ++ch) acc[ch] = (f32x4){0.f, 0.f, 0.f, 0.f};

  const float scale = 0.125f;
  int q_local = wid * 16 + lq;

  for (int step = 0; step < 13; ++step) {
    int kvb = step * 64;
    __syncthreads();
    {
      int kv = min(kvb + lane, NTOK - 1);
      const short* vr = vh + ((size_t)bh * NTOK + kv) * HEAD_DIM + wid * 16;
      bf16x8 v0 = *(const bf16x8*)vr;
      bf16x8 v1 = *(const bf16x8*)(vr + 8);
#pragma unroll
      for (int e = 0; e < 8; ++e) {
        int d = wid * 16 + e;
        vt[((d * 128 + lane * 2) ^ ((d & 7) << 4)) >> 1] = v0[e];
      }
#pragma unroll
      for (int e = 0; e < 8; ++e) {
        int d = wid * 16 + 8 + e;
        vt[((d * 128 + lane * 2) ^ ((d & 7) << 4)) >> 1] = v1[e];
      }
    }
    __syncthreads();

    float p[16];
#pragma unroll
    for (int kt = 0; kt < 4; ++kt) {
      int krow_i = min(kvb + kt * 16 + lq, NTOK - 1);
      const short* krow = kh + ((size_t)bh * NTOK + krow_i) * HEAD_DIM;
      bf16x8 aK0 = *(const bf16x8*)(krow + lg * 8);
      bf16x8 aK1 = *(const bf16x8*)(krow + 32 + lg * 8);
      f32x4 s = (f32x4){0.f, 0.f, 0.f, 0.f};
      s = __builtin_amdgcn_mfma_f32_16x16x32_bf16(aK0, bq0, s, 0, 0, 0);
      s = __builtin_amdgcn_mfma_f32_16x16x32_bf16(aK1, bq1, s, 0, 0, 0);
#pragma unroll
      for (int r = 0; r < 4; ++r) {
        int key = kvb + kt * 16 + lg * 4 + r;
        float v = s[r] * scale;
        if (key >= 1 && key < NTOK) {
          int km1 = key - 1;
          int ki = km1 / PHDIM, kj = km1 - ki * PHDIM;
          v += relh[q_local * 28 + ki] + relw[q_local * 28 + kj];
        }
        if (key >= NTOK) v = -3e30f;
        p[kt * 4 + r] = v;
      }
    }

    float pm = p[0];
#pragma unroll
    for (int i = 1; i < 16; ++i) pm = fmaxf(pm, p[i]);
    pm = fmaxf(pm, __shfl_xor(pm, 16));
    pm = fmaxf(pm, __shfl_xor(pm, 32));
    if (!__all(pm - m_l <= 8.f)) {
      float mnew = fmaxf(m_l, pm);
      float alpha = __expf(m_l - mnew);
      m_l = mnew;
      l_l *= alpha;
      if (lg == 0) axl[wid][lq] = alpha;
      f32x4 av = *(const f32x4*)&axl[wid][lg * 4];
#pragma unroll
      for (int ch = 0; ch < 4; ++ch)
#pragma unroll
        for (int r = 0; r < 4; ++r) acc[ch][r] *= av[r];
    }
    float ps = 0.f;
#pragma unroll
    for (int i = 0; i < 16; ++i) { p[i] = __expf(p[i] - m_l); ps += p[i]; }
    ps += __shfl_xor(ps, 16);
    ps += __shfl_xor(ps, 32);
    l_l += ps;

    short* pw = (short*)pbuf[wid];
#pragma unroll
    for (int kt = 0; kt < 4; ++kt) {
      unsigned lo = ((unsigned)(unsigned short)f2bf(p[kt * 4 + 0])) |
                    ((unsigned)(unsigned short)f2bf(p[kt * 4 + 1]) << 16);
      unsigned hi = ((unsigned)(unsigned short)f2bf(p[kt * 4 + 2])) |
                    ((unsigned)(unsigned short)f2bf(p[kt * 4 + 3]) << 16);
      int byte = (lq * 128 + (kt * 16 + lg * 4) * 2) ^ ((lq & 7) << 4);
      u32x2 pk; pk[0] = lo; pk[1] = hi;
      *(u32x2*)((char*)pw + byte) = pk;
    }
#pragma unroll
    for (int kc = 0; kc < 2; ++kc) {
      int pbyte = (lq * 128 + kc * 64 + lg * 16) ^ ((lq & 7) << 4);
      bf16x8 pa = *(const bf16x8*)((char*)pw + pbyte);
#pragma unroll
      for (int ch = 0; ch < 4; ++ch) {
        int d = ch * 16 + lq;
        int vbyte = (d * 128 + kc * 64 + lg * 16) ^ ((d & 7) << 4);
        bf16x8 bv = *(const bf16x8*)((char*)vt + vbyte);
        acc[ch] = __builtin_amdgcn_mfma_f32_16x16x32_bf16(pa, bv, acc[ch], 0, 0, 0);
      }
    }
  }

  if (lg == 0) axl[wid][lq] = l_l;
  f32x4 lv = *(const f32x4*)&axl[wid][lg * 4];
  int b = bh / NUM_HEADS, h = bh - b * NUM_HEADS;
#pragma unroll
  for (int r = 0; r < 4; ++r) {
    int qi = qbase + wid * 16 + lg * 4 + r;
    if (qi < NTOK) {
      float inv = 1.f / lv[r];
#pragma unroll
      for (int ch = 0; ch < 4; ++ch) {
        int d = ch * 16 + lq;
        float o = acc[ch][r] * inv + bf2f(qh[((size_t)bh * NTOK + qi) * HEAD_DIM + d]);
        Afin[((size_t)b * NTOK + qi) * DMODEL + h * HEAD_DIM + d] = f2bf(o);
      }
    }
  }
}

// ------------------------------------------------------------------- launcher
extern "C" void kernel_launch(void* const* d_in, const int* in_sizes, int n_in,
                              void* d_out, int out_size, void* d_ws, size_t ws_size,
                              hipStream_t stream)
{
  (void)in_sizes; (void)n_in; (void)out_size; (void)ws_size;
  const float* x   = (const float*)d_in[0];
  const float* pqw = (const float*)d_in[1];
  const float* pkw = (const float*)d_in[2];
  const float* pvw = (const float*)d_in[3];
  const float* gq  = (const float*)d_in[4];
  const float* bq_ = (const float*)d_in[5];
  const float* gk  = (const float*)d_in[6];
  const float* bk_ = (const float*)d_in[7];
  const float* gv  = (const float*)d_in[8];
  const float* bv_ = (const float*)d_in[9];
  const float* wq  = (const float*)d_in[10];
  const float* bqp = (const float*)d_in[11];
  const float* wk  = (const float*)d_in[12];
  const float* bkp = (const float*)d_in[13];
  const float* wv  = (const float*)d_in[14];
  const float* bvp = (const float*)d_in[15];
  const float* wp  = (const float*)d_in[16];
  const float* bpp = (const float*)d_in[17];
  const float* rph = (const float*)d_in[18];
  const float* rpw = (const float*)d_in[19];

  char* ws = (char*)d_ws;
  size_t off = 0;
  auto alloc = [&](size_t bytes) -> void* {
    void* p = ws + off; off += (bytes + 255) & ~(size_t)255; return p;
  };
  const size_t MROWS = (size_t)BATCH * NTOK;   // 12560
  short* Pq  = (short*)alloc(MROWS * DMODEL * 2);
  short* Pk  = (short*)alloc(MROWS * DMODEL * 2);
  short* Pv  = (short*)alloc(MROWS * DMODEL * 2);
  short* WqT = (short*)alloc((size_t)DMODEL * DMODEL * 2);
  short* WkT = (short*)alloc((size_t)DMODEL * DMODEL * 2);
  short* WvT = (short*)alloc((size_t)DMODEL * DMODEL * 2);
  short* WpT = (short*)alloc((size_t)DMODEL * DMODEL * 2);
  short* qhd = (short*)alloc(MROWS * DMODEL * 2 + 4096);
  short* khd = (short*)alloc(MROWS * DMODEL * 2 + 4096);
  short* vhd = (short*)alloc(MROWS * DMODEL * 2 + 4096);
  float* RelH = (float*)alloc((size_t)BHCNT * 784 * 28 * 4);
  float* RelW = (float*)alloc((size_t)BHCNT * 784 * 28 * 4);
  short* Afin = (short*)alloc(MROWS * DMODEL * 2);

  pool_ln_kernel<<<dim3(16 * 197), 192, 0, stream>>>(
      x, pqw, pkw, pvw, gq, bq_, gk, bk_, gv, bv_, Pq, Pk, Pv);
  trans_kernel<<<dim3(24, 24, 4), dim3(32, 8), 0, stream>>>(
      wq, wk, wv, wp, WqT, WkT, WvT, WpT);
  dim3 gg(99, 6);
  gemm2_kernel<<<gg, 256, 0, stream>>>(Pq, WqT, bqp, qhd, (int)MROWS, 1);
  gemm2_kernel<<<gg, 256, 0, stream>>>(Pk, WkT, bkp, khd, (int)MROWS, 1);
  gemm2_kernel<<<gg, 256, 0, stream>>>(Pv, WvT, bvp, vhd, (int)MROWS, 1);
  relbias_kernel<<<dim3(28, BHCNT, 2), 256, 0, stream>>>(qhd, rph, rpw, RelH, RelW);
  flash2_kernel<<<dim3(2496), 256, 0, stream>>>(qhd, khd, vhd, RelH, RelW, Afin);
  gemm2_kernel<<<gg, 256, 0, stream>>>(Afin, WpT, bpp, d_out, (int)MROWS, 0);
}